// Round 1
// baseline (174.667 us; speedup 1.0000x reference)
//
#include <hip/hip_runtime.h>
#include <hip/hip_bf16.h>

typedef __attribute__((ext_vector_type(8))) short bf16x8;
typedef __attribute__((ext_vector_type(4))) float f32x4;

__device__ __forceinline__ unsigned short f2bf(float x){
  union { float f; unsigned int u; } a; a.f = x;
  unsigned int r = a.u + 0x7FFFu + ((a.u >> 16) & 1u);  // RNE
  return (unsigned short)(r >> 16);
}

// Pre-pack W1 [128][512] and W2 [128][128] (fp32, torch-Linear layout) into
// bf16 fragment-ordered buffers: entry ((nt*KT + kt)*64 + lane) holds the 8
// contiguous-k bf16 of the B-fragment for n = nt*16 + (lane&15),
// k = kt*32 + (lane>>4)*8. One coalesced 16B load per frag in the main kernel.
__global__ void prep_w(const float* __restrict__ W1, const float* __restrict__ W2,
                       unsigned short* __restrict__ W1p, unsigned short* __restrict__ W2p){
  int t = blockIdx.x * 256 + threadIdx.x;       // 0..8191
  int lane = t & 63;
  int lo = lane & 15, hi = lane >> 4;
  {
    int kt = (t >> 6) & 15, nt = t >> 10;       // nt 0..7, kt 0..15
    int n = nt*16 + lo;
    int k = kt*32 + hi*8;
    const float* src = W1 + n*512 + k;
    unsigned short* dst = W1p + (size_t)t*8;
#pragma unroll
    for (int j=0;j<8;j++) dst[j] = f2bf(src[j]);
  }
  if (t < 2048){
    int kt = (t >> 6) & 3, nt = t >> 8;         // nt 0..7, kt 0..3
    int n = nt*16 + lo;
    int k = kt*32 + hi*8;
    const float* src = W2 + n*128 + k;
    unsigned short* dst = W2p + (size_t)t*8;
#pragma unroll
    for (int j=0;j<8;j++) dst[j] = f2bf(src[j]);
  }
}

// Load one K-chunk (128 cols) of the combined matrix for 64 rows into regs.
// C=0: features[nodes[row]], C=1: neigh0, C=2: neigh1, C=3: neigh2.
template<int C>
__device__ __forceinline__ void load_chunk(int brow, int tid, int B,
    const int* __restrict__ nodes, const float* __restrict__ feat,
    const float* __restrict__ g0, const float* __restrict__ g1,
    const float* __restrict__ g2, float4 v[8])
{
#pragma unroll
  for (int i=0;i<8;i++){
    int f = tid + 256*i;          // float4 index in [0, 64*32)
    int row = f >> 5;             // 32 float4 per row
    int cw  = f & 31;
    int gr = brow + row;
    gr = gr < B ? gr : (B-1);
    const float* p;
    if      (C==0) p = feat + (size_t)nodes[gr] * 128;
    else if (C==1) p = g0 + (size_t)gr * 128;
    else if (C==2) p = g1 + (size_t)gr * 128;
    else           p = g2 + (size_t)gr * 128;
    v[i] = reinterpret_cast<const float4*>(p)[cw];
  }
}

// Scale, convert to bf16, store into swizzled LDS tile [64][128] bf16.
// Swizzle: byte ^= (row&7)<<4  (spreads row-stride-256B reads across banks).
__device__ __forceinline__ void write_chunk(unsigned short* buf, int tid, float s,
                                            const float4 v[8])
{
  char* base = reinterpret_cast<char*>(buf);
#pragma unroll
  for (int i=0;i<8;i++){
    int f = tid + 256*i;
    int row = f >> 5;
    int cw  = f & 31;
    int byte = row*256 + ((cw*8) ^ ((row & 7) << 4));
    uint2 val;
    val.x = f2bf(v[i].x*s) | ((unsigned int)f2bf(v[i].y*s) << 16);
    val.y = f2bf(v[i].z*s) | ((unsigned int)f2bf(v[i].w*s) << 16);
    *reinterpret_cast<uint2*>(base + byte) = val;
  }
}

// One K=128 chunk of GEMM1: wave wv computes its 16 rows x 128 cols.
__device__ __forceinline__ void gemm1_chunk(const unsigned short* buf,
    int wv, int lo, int hi, int lane, int chunk,
    const bf16x8* __restrict__ W1f, f32x4 acc[8])
{
  const char* base = reinterpret_cast<const char*>(buf);
  bf16x8 a[4];
  int row = wv*16 + lo;
  int swz = (row & 7) << 4;
  int rb  = row * 256;
#pragma unroll
  for (int kt=0; kt<4; kt++){
    int colb = kt*64 + hi*16;
    a[kt] = *reinterpret_cast<const bf16x8*>(base + rb + (colb ^ swz));
  }
#pragma unroll
  for (int nt=0; nt<8; nt++){
#pragma unroll
    for (int kt=0; kt<4; kt++){
      bf16x8 b = W1f[(nt*16 + chunk*4 + kt)*64 + lane];
      acc[nt] = __builtin_amdgcn_mfma_f32_16x16x32_bf16(a[kt], b, acc[nt], 0, 0, 0);
    }
  }
}

__global__ __launch_bounds__(256, 2) void enc_main(
    const int* __restrict__ nodes, const float* __restrict__ feat,
    const float* __restrict__ g0, const float* __restrict__ g1,
    const float* __restrict__ g2,
    const unsigned short* __restrict__ W1p, const float* __restrict__ b1,
    const unsigned short* __restrict__ W2p, const float* __restrict__ b2,
    float* __restrict__ out, int B)
{
  __shared__ unsigned short abuf[2][64*128];  // 2 x 16 KB, swizzled A chunks
  __shared__ unsigned short hbuf[4][16*128];  // 4 KB per wave: h transpose

  const int tid  = threadIdx.x;
  const int lane = tid & 63;
  const int wv   = tid >> 6;
  const int lo   = lane & 15, hi = lane >> 4;
  const int brow = blockIdx.x * 64;

  const bf16x8* W1f = reinterpret_cast<const bf16x8*>(W1p);
  const bf16x8* W2f = reinterpret_cast<const bf16x8*>(W2p);

  // acc1 init = b1 broadcast (D col = lane&15 + 16*nt, rows in regs)
  f32x4 acc1[8];
#pragma unroll
  for (int nt=0;nt<8;nt++){ float bb = b1[lo + 16*nt]; acc1[nt] = (f32x4){bb,bb,bb,bb}; }

  float4 v[8];
  // prologue: chunk0 (gather) -> abuf[0]
  load_chunk<0>(brow, tid, B, nodes, feat, g0, g1, g2, v);
  write_chunk(abuf[0], tid, 1.0f, v);
  __syncthreads();

  // c=0: prefetch chunk1, compute chunk0
  load_chunk<1>(brow, tid, B, nodes, feat, g0, g1, g2, v);
  gemm1_chunk(abuf[0], wv, lo, hi, lane, 0, W1f, acc1);
  write_chunk(abuf[1], tid, 1.0f, v);
  __syncthreads();

  // c=1: prefetch chunk2 (x0.5), compute chunk1
  load_chunk<2>(brow, tid, B, nodes, feat, g0, g1, g2, v);
  gemm1_chunk(abuf[1], wv, lo, hi, lane, 1, W1f, acc1);
  write_chunk(abuf[0], tid, 0.5f, v);
  __syncthreads();

  // c=2: prefetch chunk3 (x2.0), compute chunk2
  load_chunk<3>(brow, tid, B, nodes, feat, g0, g1, g2, v);
  gemm1_chunk(abuf[0], wv, lo, hi, lane, 2, W1f, acc1);
  write_chunk(abuf[1], tid, 2.0f, v);
  __syncthreads();

  // c=3: compute chunk3
  gemm1_chunk(abuf[1], wv, lo, hi, lane, 3, W1f, acc1);

  // tanh -> bf16 -> per-wave swizzled LDS tile [16][128] (transpose for GEMM2 A-frags)
  char* hbase = reinterpret_cast<char*>(hbuf[wv]);
#pragma unroll
  for (int nt=0;nt<8;nt++){
#pragma unroll
    for (int r=0;r<4;r++){
      float x = acc1[nt][r];
      float t = 1.0f - 2.0f * __builtin_amdgcn_rcpf(__expf(2.0f*x) + 1.0f);
      int row = hi*4 + r;              // local b-row 0..15
      int colb = (lo + 16*nt) * 2;     // byte col
      *reinterpret_cast<unsigned short*>(hbase + row*256 + (colb ^ ((row&7)<<4))) = f2bf(t);
    }
  }
  __syncthreads();   // robust cross-lane LDS visibility (per-wave region, cheap)

  // GEMM2: out_tile = h_tile @ W2^T + b2
  f32x4 acc2[8];
#pragma unroll
  for (int nt=0;nt<8;nt++){ float bb = b2[lo + 16*nt]; acc2[nt] = (f32x4){bb,bb,bb,bb}; }

  bf16x8 a2[4];
  {
    int row = lo;
    int swz = (row & 7) << 4;
#pragma unroll
    for (int kt=0;kt<4;kt++){
      int colb = kt*64 + hi*16;
      a2[kt] = *reinterpret_cast<const bf16x8*>(hbase + row*256 + (colb ^ swz));
    }
  }
#pragma unroll
  for (int nt=0;nt<8;nt++){
#pragma unroll
    for (int kt=0;kt<4;kt++){
      bf16x8 b = W2f[(nt*4 + kt)*64 + lane];
      acc2[nt] = __builtin_amdgcn_mfma_f32_16x16x32_bf16(a2[kt], b, acc2[nt], 0, 0, 0);
    }
  }

  // store: lane holds out[row = hi*4+r][col = lo+16*nt]
  int rbase = brow + wv*16 + hi*4;
#pragma unroll
  for (int r=0;r<4;r++){
    int gr = rbase + r;
    if (gr < B){
      float* op = out + (size_t)gr*128 + lo;
#pragma unroll
      for (int nt=0;nt<8;nt++) op[16*nt] = acc2[nt][r];
    }
  }
}

extern "C" void kernel_launch(void* const* d_in, const int* in_sizes, int n_in,
                              void* d_out, int out_size, void* d_ws, size_t ws_size,
                              hipStream_t stream) {
  const int*   nodes = (const int*)  d_in[0];
  const float* feat  = (const float*)d_in[1];
  const float* g0    = (const float*)d_in[2];
  const float* g1    = (const float*)d_in[3];
  const float* g2    = (const float*)d_in[4];
  const float* W1    = (const float*)d_in[5];
  const float* b1    = (const float*)d_in[6];
  const float* W2    = (const float*)d_in[7];
  const float* b2    = (const float*)d_in[8];
  float* out = (float*)d_out;
  const int B = in_sizes[0];

  unsigned short* W1p = (unsigned short*)d_ws;          // 8192 frags * 16B = 128 KB
  unsigned short* W2p = W1p + 8192*8;                   // 2048 frags * 16B =  32 KB

  prep_w<<<32, 256, 0, stream>>>(W1, W2, W1p, W2p);
  int grid = (B + 63) / 64;
  enc_main<<<grid, 256, 0, stream>>>(nodes, feat, g0, g1, g2, W1p, b1, W2p, b2, out, B);
}

// Round 2
// 133.190 us; speedup vs baseline: 1.3114x; 1.3114x over previous
//
#include <hip/hip_runtime.h>
#include <hip/hip_bf16.h>

typedef __attribute__((ext_vector_type(8))) short bf16x8;
typedef __attribute__((ext_vector_type(4))) float f32x4;

__device__ __forceinline__ unsigned short f2bf(float x){
  union { float f; unsigned int u; } a; a.f = x;
  unsigned int r = a.u + 0x7FFFu + ((a.u >> 16) & 1u);  // RNE
  return (unsigned short)(r >> 16);
}

__device__ __forceinline__ void glds16(const void* g, void* l){
  __builtin_amdgcn_global_load_lds(
      (const __attribute__((address_space(1))) unsigned int*)g,
      (__attribute__((address_space(3))) unsigned int*)l,
      16, 0, 0);
}

// -------- prep: pack W1 (channel-weights folded, PHASE-ordered) and W2 --------
// Phase order of K-tiles: P0/P1 = neigh0 (k 128..255), P2/P3 = self (k 0..127),
// P4/P5 = neigh1 (k 256..383, x0.5), P6/P7 = neigh2 (k 384..511, x2.0).
// W1p entry ((P*8+nt)*2+k2)*64+lane holds 8 bf16: n = nt*16+(lane&15),
// k = tile_k*32 + (lane>>4)*8. Each phase slice is a contiguous 16 KB.
__global__ void prep_w(const float* __restrict__ W1, const float* __restrict__ W2,
                       unsigned short* __restrict__ W1p, unsigned short* __restrict__ W2p){
  int t = blockIdx.x * 256 + threadIdx.x;       // 0..8191
  int lane = t & 63;
  int lo = lane & 15, hi = lane >> 4;
  {
    int ktg = (t >> 6) & 15, nt = t >> 10;      // ktg 0..15 (global k-tile), nt 0..7
    int c = ktg >> 2;                            // 0 self, 1 n0, 2 n1, 3 n2
    int base = (c==0) ? 2 : ((c==1) ? 0 : 2*c);  // phase base per channel
    int P = base + ((ktg >> 1) & 1);
    int k2 = ktg & 1;
    float s = (c==2) ? 0.5f : ((c==3) ? 2.0f : 1.0f);
    int n = nt*16 + lo;
    int k = ktg*32 + hi*8;
    const float* src = W1 + n*512 + k;
    unsigned short* dst = W1p + ((size_t)((P*8 + nt)*2 + k2)*64 + lane)*8;
#pragma unroll
    for (int j=0;j<8;j++) dst[j] = f2bf(src[j]*s);
  }
  if (t < 2048){
    int kt = (t >> 6) & 3, nt = t >> 8;
    int n = nt*16 + lo;
    int k = kt*32 + hi*8;
    const float* src = W2 + n*128 + k;
    unsigned short* dst = W2p + (size_t)t*8;
#pragma unroll
    for (int j=0;j<8;j++) dst[j] = f2bf(src[j]);
  }
}

// -------- staging: 64 rows x 64 fp32 half-row per phase, src-side XOR swizzle --
// LDS layout: row*256B + gs*16B (linear, as global_load_lds requires).
// stored[gs] = orig[gs ^ (row&7)]  ->  reader uses addr granule g ^ (row&7).
__device__ __forceinline__ void stage_neigh(char* db, int wv, int lane, int brow,
                                            const float* g, int half, int B){
  int r4 = lane >> 4, gs = lane & 15;
#pragma unroll
  for (int j=0;j<4;j++){
    int row = 4*(wv*4 + j) + r4;
    int gr = brow + row; gr = gr < B ? gr : (B-1);
    const char* src = (const char*)(g + (size_t)gr*128 + half*64) + ((gs ^ (row & 7)) << 4);
    glds16(src, db + row*256 + (gs << 4));
  }
}
__device__ __forceinline__ void stage_gather(char* db, int wv, int lane,
                                             const float* feat, const int* nid, int half){
  int r4 = lane >> 4, gs = lane & 15;
#pragma unroll
  for (int j=0;j<4;j++){
    int row = 4*(wv*4 + j) + r4;
    const char* src = (const char*)(feat + (size_t)nid[j]*128 + half*64) + ((gs ^ (row & 7)) << 4);
    glds16(src, db + row*256 + (gs << 4));
  }
}
__device__ __forceinline__ void stage_w(char* wb, int wv, int lane,
                                        const unsigned short* W1p, int P){
  const char* src = (const char*)W1p + (size_t)P*16384 + (wv*4)*1024 + (lane << 4);
#pragma unroll
  for (int j=0;j<4;j++)
    glds16(src + j*1024, wb + (wv*4 + j)*1024 + (lane << 4));
}

// -------- one phase of GEMM1: pure LDS + MFMA (no vmem -> no vmcnt drains) ----
__device__ __forceinline__ void gemm_phase(const char* db, const char* wb,
    int wv, int lo, int hi, int lane, f32x4 acc[8])
{
  int row = wv*16 + lo;
  int s = row & 7;
  const char* rb = db + row*256;
  bf16x8 a[2];
#pragma unroll
  for (int k2=0;k2<2;k2++){
    int g0 = (8*k2 + 2*hi) ^ s;                // 16B-granule of k[0..3]
    float4 x = *(const float4*)(rb + (g0 << 4));
    float4 y = *(const float4*)(rb + ((g0 ^ 1) << 4));
    bf16x8 t;
    t[0]=(short)f2bf(x.x); t[1]=(short)f2bf(x.y); t[2]=(short)f2bf(x.z); t[3]=(short)f2bf(x.w);
    t[4]=(short)f2bf(y.x); t[5]=(short)f2bf(y.y); t[6]=(short)f2bf(y.z); t[7]=(short)f2bf(y.w);
    a[k2] = t;
  }
#pragma unroll
  for (int nt=0;nt<8;nt++){
#pragma unroll
    for (int k2=0;k2<2;k2++){
      bf16x8 b = *(const bf16x8*)(wb + (((nt*2 + k2)*64 + lane) << 4));
      acc[nt] = __builtin_amdgcn_mfma_f32_16x16x32_bf16(a[k2], b, acc[nt], 0, 0, 0);
    }
  }
}

#define PH_WAIT8 asm volatile("s_waitcnt vmcnt(8)" ::: "memory")
#define PH_WAIT0 asm volatile("s_waitcnt vmcnt(0)" ::: "memory")
#define BAR do{ asm volatile("" ::: "memory"); __builtin_amdgcn_s_barrier(); \
                asm volatile("" ::: "memory"); }while(0)

__global__ __launch_bounds__(256, 2) void enc_main(
    const int* __restrict__ nodes, const float* __restrict__ feat,
    const float* __restrict__ g0, const float* __restrict__ g1,
    const float* __restrict__ g2,
    const unsigned short* __restrict__ W1p, const float* __restrict__ b1,
    const unsigned short* __restrict__ W2p, const float* __restrict__ b2,
    float* __restrict__ out, int B)
{
  __shared__ char smem[65536];
  char* DB0 = smem;            char* DB1 = smem + 16384;
  char* WB0 = smem + 32768;    char* WB1 = smem + 49152;

  const int tid  = threadIdx.x;
  const int lane = tid & 63;
  const int wv   = tid >> 6;
  const int lo   = lane & 15, hi = lane >> 4;
  const int brow = blockIdx.x * 64;

  // bias + node-index loads FIRST (oldest vmem -> their compiler waits never
  // drain the staging queue)
  float bb1[8];
#pragma unroll
  for (int nt=0;nt<8;nt++) bb1[nt] = b1[lo + 16*nt];
  int nid[4];
  {
    int r4 = lane >> 4;
#pragma unroll
    for (int j=0;j<4;j++){
      int r = brow + 4*(wv*4 + j) + r4;
      r = r < B ? r : (B-1);
      nid[j] = nodes[r];
    }
  }
  asm volatile("" ::: "memory");   // pin the loads above the stages

  // prologue: stage P0 (n0 half0) and P1 (n0 half1)
  stage_neigh(DB0, wv, lane, brow, g0, 0, B);  stage_w(WB0, wv, lane, W1p, 0);
  stage_neigh(DB1, wv, lane, brow, g0, 1, B);  stage_w(WB1, wv, lane, W1p, 1);

  f32x4 acc[8];
#pragma unroll
  for (int nt=0;nt<8;nt++) acc[nt] = (f32x4){bb1[nt],bb1[nt],bb1[nt],bb1[nt]};

  // phase 0: n0 half0
  PH_WAIT8; BAR;
  gemm_phase(DB0, WB0, wv, lo, hi, lane, acc);
  BAR;
  stage_gather(DB0, wv, lane, feat, nid, 0);   stage_w(WB0, wv, lane, W1p, 2);
  // phase 1: n0 half1
  PH_WAIT8; BAR;
  gemm_phase(DB1, WB1, wv, lo, hi, lane, acc);
  BAR;
  stage_gather(DB1, wv, lane, feat, nid, 1);   stage_w(WB1, wv, lane, W1p, 3);
  // phase 2: self half0
  PH_WAIT8; BAR;
  gemm_phase(DB0, WB0, wv, lo, hi, lane, acc);
  BAR;
  stage_neigh(DB0, wv, lane, brow, g1, 0, B);  stage_w(WB0, wv, lane, W1p, 4);
  // phase 3: self half1
  PH_WAIT8; BAR;
  gemm_phase(DB1, WB1, wv, lo, hi, lane, acc);
  BAR;
  stage_neigh(DB1, wv, lane, brow, g1, 1, B);  stage_w(WB1, wv, lane, W1p, 5);
  // phase 4: n1 half0
  PH_WAIT8; BAR;
  gemm_phase(DB0, WB0, wv, lo, hi, lane, acc);
  BAR;
  stage_neigh(DB0, wv, lane, brow, g2, 0, B);  stage_w(WB0, wv, lane, W1p, 6);
  // phase 5: n1 half1
  PH_WAIT8; BAR;
  gemm_phase(DB1, WB1, wv, lo, hi, lane, acc);
  BAR;
  stage_neigh(DB1, wv, lane, brow, g2, 1, B);  stage_w(WB1, wv, lane, W1p, 7);
  // phase 6: n2 half0
  PH_WAIT8; BAR;
  gemm_phase(DB0, WB0, wv, lo, hi, lane, acc);
  BAR;
  // phase 7: n2 half1
  PH_WAIT0; BAR;
  gemm_phase(DB1, WB1, wv, lo, hi, lane, acc);

  // ---- tanh -> bf16 -> per-wave swizzled LDS tile (overlay on WB0, free now) --
  char* hbase = WB0 + wv*4096;
#pragma unroll
  for (int nt=0;nt<8;nt++){
#pragma unroll
    for (int r=0;r<4;r++){
      float x = acc[nt][r];
      float t = 1.0f - 2.0f * __builtin_amdgcn_rcpf(__expf(2.0f*x) + 1.0f);
      int row = hi*4 + r;
      int colb = (lo + 16*nt)*2;
      *(unsigned short*)(hbase + row*256 + (colb ^ ((row & 7) << 4))) = f2bf(t);
    }
  }
  __syncthreads();   // safe full drain: staging queue is empty here

  // ---- GEMM2: out = h @ W2^T + b2 ----
  const bf16x8* W2f = (const bf16x8*)W2p;
  f32x4 acc2[8];
#pragma unroll
  for (int nt=0;nt<8;nt++){ float v2 = b2[lo + 16*nt]; acc2[nt] = (f32x4){v2,v2,v2,v2}; }

  bf16x8 a2[4];
  {
    int row = lo;
    int swz = (row & 7) << 4;
#pragma unroll
    for (int kt=0;kt<4;kt++){
      int colb = kt*64 + hi*16;
      a2[kt] = *(const bf16x8*)(hbase + row*256 + (colb ^ swz));
    }
  }
#pragma unroll
  for (int nt=0;nt<8;nt++){
#pragma unroll
    for (int kt=0;kt<4;kt++){
      bf16x8 b = W2f[(nt*4 + kt)*64 + lane];
      acc2[nt] = __builtin_amdgcn_mfma_f32_16x16x32_bf16(a2[kt], b, acc2[nt], 0, 0, 0);
    }
  }

  // store: lane holds out[row = wv*16 + hi*4 + r][col = lo + 16*nt]
  int rbase = brow + wv*16 + hi*4;
#pragma unroll
  for (int r=0;r<4;r++){
    int gr = rbase + r;
    if (gr < B){
      float* op = out + (size_t)gr*128 + lo;
#pragma unroll
      for (int nt=0;nt<8;nt++) op[16*nt] = acc2[nt][r];
    }
  }
}

extern "C" void kernel_launch(void* const* d_in, const int* in_sizes, int n_in,
                              void* d_out, int out_size, void* d_ws, size_t ws_size,
                              hipStream_t stream) {
  const int*   nodes = (const int*)  d_in[0];
  const float* feat  = (const float*)d_in[1];
  const float* g0    = (const float*)d_in[2];
  const float* g1    = (const float*)d_in[3];
  const float* g2    = (const float*)d_in[4];
  const float* W1    = (const float*)d_in[5];
  const float* b1    = (const float*)d_in[6];
  const float* W2    = (const float*)d_in[7];
  const float* b2    = (const float*)d_in[8];
  float* out = (float*)d_out;
  const int B = in_sizes[0];

  unsigned short* W1p = (unsigned short*)d_ws;          // 128 KB, phase-ordered
  unsigned short* W2p = W1p + 8192*8;                   // 32 KB

  prep_w<<<32, 256, 0, stream>>>(W1, W2, W1p, W2p);
  int grid = (B + 63) / 64;
  enc_main<<<grid, 256, 0, stream>>>(nodes, feat, g0, g1, g2, W1p, b1, W2p, b2, out, B);
}

// Round 3
// 117.598 us; speedup vs baseline: 1.4853x; 1.1326x over previous
//
#include <hip/hip_runtime.h>
#include <hip/hip_bf16.h>

typedef __attribute__((ext_vector_type(8))) short bf16x8;
typedef __attribute__((ext_vector_type(4))) float f32x4;

__device__ __forceinline__ unsigned short f2bf(float x){
  union { float f; unsigned int u; } a; a.f = x;
  unsigned int r = a.u + 0x7FFFu + ((a.u >> 16) & 1u);  // RNE
  return (unsigned short)(r >> 16);
}
__device__ __forceinline__ short bfc(float x){
  __hip_bfloat16 h = __float2bfloat16(x);           // compiler -> v_cvt_pk_bf16_f32
  union { __hip_bfloat16 h; short s; } u; u.h = h;
  return u.s;
}

__device__ __forceinline__ void glds16(const void* g, void* l){
  __builtin_amdgcn_global_load_lds(
      (const __attribute__((address_space(1))) unsigned int*)g,
      (__attribute__((address_space(3))) unsigned int*)l,
      16, 0, 0);
}
__device__ __forceinline__ void gl16(bf16x8* d, const char* p){
  asm volatile("global_load_dwordx4 %0, %1, off" : "=v"(*d) : "v"(p) : "memory");
}

// ---- prep: W1 bf16, channel weights folded, (phase,wave,nt2,k2)-ordered ----
// W1p entry e = (((P*4+wv)*2+nt2)*2+k2)*64+lane holds 8 bf16 of the B-frag:
// n = wv*32+nt2*16+(lane&15), k = ktg*32+(lane>>4)*8 where ktg maps phase P
// to the concat order [self | n0 | n1*0.5 | n2*2.0]; phases consume
// n0,n0,self,self,n1,n1,n2,n2.
__global__ void prep_w(const float* __restrict__ W1, const float* __restrict__ W2,
                       unsigned short* __restrict__ W1p, unsigned short* __restrict__ W2p){
  int t = blockIdx.x * 256 + threadIdx.x;       // 0..8191
  int lane = t & 63;
  int lo = lane & 15, hi = lane >> 4;
  {
    int entry = t >> 6;                         // 0..127
    int k2 = entry & 1, nt2 = (entry>>1)&1, wv = (entry>>2)&3, P = entry>>4;
    int pb = P >> 1;
    int c = (pb==0) ? 1 : (pb==1) ? 0 : pb;     // channel: P0/1=n0, P2/3=self, P4/5=n1, P6/7=n2
    int ktg = c*4 + (P&1)*2 + k2;               // global k-tile 0..15
    float s = (c==2) ? 0.5f : (c==3) ? 2.0f : 1.0f;
    int n = wv*32 + nt2*16 + lo;
    int k = ktg*32 + hi*8;
    const float* src = W1 + n*512 + k;
    unsigned short* dst = W1p + (size_t)t*8;
#pragma unroll
    for (int j=0;j<8;j++) dst[j] = f2bf(src[j]*s);
  }
  if (t < 2048){
    int entry = t >> 6;                         // 0..31
    int kt = entry & 3, nt2 = (entry>>2)&1, wv = (entry>>3)&3;
    int n = wv*32 + nt2*16 + lo;
    int k = kt*32 + hi*8;
    const float* src = W2 + n*128 + k;
    unsigned short* dst = W2p + (size_t)t*8;
#pragma unroll
    for (int j=0;j<8;j++) dst[j] = f2bf(src[j]);
  }
}

// ---- staging: 64 rows x 64 fp32 per phase, src-side XOR swizzle ----
__device__ __forceinline__ void stage_neigh(char* db, int wv, int lane, int brow,
                                            const float* g, int half, int B){
  int r4 = lane >> 4, gs = lane & 15;
#pragma unroll
  for (int j=0;j<4;j++){
    int row = 4*(wv*4 + j) + r4;
    int gr = brow + row; gr = gr < B ? gr : (B-1);
    const char* src = (const char*)(g + (size_t)gr*128 + half*64) + ((gs ^ (row & 7)) << 4);
    glds16(src, db + row*256 + (gs << 4));
  }
}
__device__ __forceinline__ void stage_gather(char* db, int wv, int lane,
                                             const float* feat, const int* nid, int half){
  int r4 = lane >> 4, gs = lane & 15;
#pragma unroll
  for (int j=0;j<4;j++){
    int row = 4*(wv*4 + j) + r4;
    const char* src = (const char*)(feat + (size_t)nid[j]*128 + half*64) + ((gs ^ (row & 7)) << 4);
    glds16(src, db + row*256 + (gs << 4));
  }
}
// W frags for one phase: 4 x dwordx4 into regs (L2-resident)
__device__ __forceinline__ void loadW(bf16x8 w[2][2], const char* W1p, int wv, int lane, int P){
  const char* base = W1p + (size_t)(P*4 + wv)*4096 + (lane << 4);
  gl16(&w[0][0], base);
  gl16(&w[0][1], base + 1024);
  gl16(&w[1][0], base + 2048);
  gl16(&w[1][1], base + 3072);
}

// ---- one phase: wave computes 64 rows x 32 cols, K=64. Pure LDS+MFMA. ----
__device__ __forceinline__ void gemm_phase(const char* db, const bf16x8 w[2][2],
    int lo, int hi, f32x4 acc[4][2])
{
#pragma unroll
  for (int rt=0;rt<4;rt++){
    int row = rt*16 + lo;
    int s = row & 7;
    const char* rb = db + row*256;
    bf16x8 a[2];
#pragma unroll
    for (int k2=0;k2<2;k2++){
      int g0 = (8*k2 + 2*hi) ^ s;
      float4 x = *(const float4*)(rb + (g0 << 4));
      float4 y = *(const float4*)(rb + ((g0 ^ 1) << 4));
      bf16x8 t;
      t[0]=bfc(x.x); t[1]=bfc(x.y); t[2]=bfc(x.z); t[3]=bfc(x.w);
      t[4]=bfc(y.x); t[5]=bfc(y.y); t[6]=bfc(y.z); t[7]=bfc(y.w);
      a[k2] = t;
    }
#pragma unroll
    for (int nt2=0;nt2<2;nt2++)
#pragma unroll
      for (int k2=0;k2<2;k2++)
        acc[rt][nt2] = __builtin_amdgcn_mfma_f32_16x16x32_bf16(a[k2], w[nt2][k2], acc[rt][nt2], 0, 0, 0);
  }
}

#define WAITN(n) do{ asm volatile("s_waitcnt vmcnt(" #n ")" ::: "memory"); \
                     __builtin_amdgcn_sched_barrier(0); }while(0)
#define BAR do{ __builtin_amdgcn_sched_barrier(0); __builtin_amdgcn_s_barrier(); \
                __builtin_amdgcn_sched_barrier(0); }while(0)

__global__ __launch_bounds__(256, 3) void enc_main(
    const int* __restrict__ nodes, const float* __restrict__ feat,
    const float* __restrict__ g0, const float* __restrict__ g1,
    const float* __restrict__ g2,
    const unsigned short* __restrict__ W1p, const float* __restrict__ b1,
    const unsigned short* __restrict__ W2p, const float* __restrict__ b2,
    float* __restrict__ out, int B)
{
  __shared__ char smem[49152];
  char* DB0 = smem;  char* DB1 = smem + 16384;  char* DB2 = smem + 32768;

  const int tid  = threadIdx.x;
  const int lane = tid & 63;
  const int wv   = tid >> 6;
  const int lo   = lane & 15, hi = lane >> 4;
  const int brow = blockIdx.x * 64;
  const char* W1c = (const char*)W1p;

  // oldest vmem: biases + node indices; pin completion BEFORE any staging so
  // compiler waits for them never drain the pipeline queue.
  float bb1[2];
  bb1[0] = b1[wv*32 + lo];  bb1[1] = b1[wv*32 + 16 + lo];
  int nid[4];
  {
    int r4 = lane >> 4;
#pragma unroll
    for (int j=0;j<4;j++){
      int r = brow + 4*(wv*4 + j) + r4;
      r = r < B ? r : (B-1);
      nid[j] = nodes[r];
    }
  }
  asm volatile("" :: "v"(nid[0]), "v"(nid[1]), "v"(nid[2]), "v"(nid[3]),
                     "v"(bb1[0]), "v"(bb1[1]) : "memory");

  bf16x8 w0[2][2], w1[2][2], w2[2][2];
  // prologue: data P0,P1 + W P0,P1
  stage_neigh(DB0, wv, lane, brow, g0, 0, B);     // D0
  stage_neigh(DB1, wv, lane, brow, g0, 1, B);     // D1
  loadW(w0, W1c, wv, lane, 0);                    // W0
  loadW(w1, W1c, wv, lane, 1);                    // W1

  f32x4 acc[4][2];
#pragma unroll
  for (int rt=0;rt<4;rt++)
#pragma unroll
    for (int nt2=0;nt2<2;nt2++)
      acc[rt][nt2] = (f32x4){bb1[nt2],bb1[nt2],bb1[nt2],bb1[nt2]};

  // ---- phase 0 (n0 h0) ----
  stage_gather(DB2, wv, lane, feat, nid, 0);      // D2
  loadW(w2, W1c, wv, lane, 2);                    // W2
  WAITN(12); BAR;
  gemm_phase(DB0, w0, lo, hi, acc);
  BAR;
  // ---- phase 1 (n0 h1) ----
  stage_gather(DB0, wv, lane, feat, nid, 1);      // D3
  loadW(w0, W1c, wv, lane, 3);                    // W3
  WAITN(16); BAR;
  gemm_phase(DB1, w1, lo, hi, acc);
  BAR;
  // ---- phase 2 (self h0) ----
  stage_neigh(DB1, wv, lane, brow, g1, 0, B);     // D4
  loadW(w1, W1c, wv, lane, 4);                    // W4
  WAITN(16); BAR;
  gemm_phase(DB2, w2, lo, hi, acc);
  BAR;
  // ---- phase 3 (self h1) ----
  stage_neigh(DB2, wv, lane, brow, g1, 1, B);     // D5
  loadW(w2, W1c, wv, lane, 5);                    // W5
  WAITN(16); BAR;
  gemm_phase(DB0, w0, lo, hi, acc);
  BAR;
  // ---- phase 4 (n1 h0) ----
  stage_neigh(DB0, wv, lane, brow, g2, 0, B);     // D6
  loadW(w0, W1c, wv, lane, 6);                    // W6
  WAITN(16); BAR;
  gemm_phase(DB1, w1, lo, hi, acc);
  BAR;
  // ---- phase 5 (n1 h1) ----
  stage_neigh(DB1, wv, lane, brow, g2, 1, B);     // D7
  loadW(w1, W1c, wv, lane, 7);                    // W7
  WAITN(16); BAR;
  gemm_phase(DB2, w2, lo, hi, acc);
  BAR;
  // ---- phase 6 (n2 h0) ----
  WAITN(8); BAR;
  gemm_phase(DB0, w0, lo, hi, acc);
  BAR;
  // ---- phase 7 (n2 h1) ----
  WAITN(0); BAR;
  gemm_phase(DB1, w1, lo, hi, acc);

  // W2 frags (L2) — plain loads, overlap tanh
  const bf16x8* W2f = (const bf16x8*)W2p;
  bf16x8 w2r[2][4];
#pragma unroll
  for (int nt2=0;nt2<2;nt2++)
#pragma unroll
    for (int kt=0;kt<4;kt++)
      w2r[nt2][kt] = W2f[(size_t)((wv*2 + nt2)*4 + kt)*64 + lane];

  // tanh -> bf16 -> swizzled h tile [64][128] bf16 (overlay DB0..; all staging drained)
  char* hbase = smem;   // 16 KB
#pragma unroll
  for (int rt=0;rt<4;rt++){
#pragma unroll
    for (int nt2=0;nt2<2;nt2++){
#pragma unroll
      for (int r=0;r<4;r++){
        float x = acc[rt][nt2][r];
        float t = 1.0f - 2.0f * __builtin_amdgcn_rcpf(__expf(2.0f*x) + 1.0f);
        int row = rt*16 + hi*4 + r;
        int colb = (wv*32 + nt2*16 + lo) * 2;
        *(unsigned short*)(hbase + row*256 + (colb ^ ((row & 7) << 4))) = f2bf(t);
      }
    }
  }
  __syncthreads();

  // GEMM2: out[64 x (wave's 32 cols)] = h @ W2^T + b2
  float bb2[2];
  bb2[0] = b2[wv*32 + lo];  bb2[1] = b2[wv*32 + 16 + lo];

#pragma unroll
  for (int rt=0;rt<4;rt++){
    f32x4 acc2[2];
    acc2[0] = (f32x4){bb2[0],bb2[0],bb2[0],bb2[0]};
    acc2[1] = (f32x4){bb2[1],bb2[1],bb2[1],bb2[1]};
    int row = rt*16 + lo;
    int swz = (row & 7) << 4;
    const char* rb = hbase + row*256;
    bf16x8 a2[4];
#pragma unroll
    for (int kt=0;kt<4;kt++){
      int colb = kt*64 + hi*16;
      a2[kt] = *(const bf16x8*)(rb + (colb ^ swz));
    }
#pragma unroll
    for (int nt2=0;nt2<2;nt2++)
#pragma unroll
      for (int kt=0;kt<4;kt++)
        acc2[nt2] = __builtin_amdgcn_mfma_f32_16x16x32_bf16(a2[kt], w2r[nt2][kt], acc2[nt2], 0, 0, 0);

    int rbase = brow + rt*16 + hi*4;
#pragma unroll
    for (int r=0;r<4;r++){
      int gr = rbase + r;
      if (gr < B){
        float* op = out + (size_t)gr*128 + wv*32 + lo;
        op[0]  = acc2[0][r];
        op[16] = acc2[1][r];
      }
    }
  }
}

extern "C" void kernel_launch(void* const* d_in, const int* in_sizes, int n_in,
                              void* d_out, int out_size, void* d_ws, size_t ws_size,
                              hipStream_t stream) {
  const int*   nodes = (const int*)  d_in[0];
  const float* feat  = (const float*)d_in[1];
  const float* g0    = (const float*)d_in[2];
  const float* g1    = (const float*)d_in[3];
  const float* g2    = (const float*)d_in[4];
  const float* W1    = (const float*)d_in[5];
  const float* b1    = (const float*)d_in[6];
  const float* W2    = (const float*)d_in[7];
  const float* b2    = (const float*)d_in[8];
  float* out = (float*)d_out;
  const int B = in_sizes[0];

  unsigned short* W1p = (unsigned short*)d_ws;          // 128 KB, (P,wv,nt2,k2)-ordered
  unsigned short* W2p = W1p + 8192*8;                   // 32 KB

  prep_w<<<32, 256, 0, stream>>>(W1, W2, W1p, W2p);
  int grid = (B + 63) / 64;
  enc_main<<<grid, 256, 0, stream>>>(nodes, feat, g0, g1, g2, W1p, b1, W2p, b2, out, B);
}